// Round 1
// baseline (345.021 us; speedup 1.0000x reference)
//
#include <hip/hip_runtime.h>

// ---------------------------------------------------------------------------
// MHA (GQA + RoPE, non-causal) on MI355X, bf16 MFMA pipeline, fp32 in/out.
// B=2 S=2048 D=2048 H=16 KV=4 hd=128.
// ---------------------------------------------------------------------------

typedef __attribute__((ext_vector_type(8))) short short8;
typedef __attribute__((ext_vector_type(4))) float f32x4;

#define DEV static __device__ __forceinline__

#define NB 2
#define NS 2048
#define ND 2048
#define NH 16
#define NKV 4
#define HD 128
#define NQKV 3072   // H*hd + 2*KV*hd

DEV unsigned short f2bf(float f) {
  union { float f; unsigned u; } v; v.f = f;
  unsigned r = v.u + 0x7fffu + ((v.u >> 16) & 1u);   // RNE
  return (unsigned short)(r >> 16);
}
DEV float bf2f(unsigned short u) {
  union { unsigned u; float f; } v; v.u = ((unsigned)u) << 16; return v.f;
}

typedef const __attribute__((address_space(1))) void* gas1_t;
typedef __attribute__((address_space(3))) void* las3_t;
DEV void gload16(const void* g, void* l) {
  // global -> LDS direct, 16B/lane; LDS dest = wave-uniform base + lane*16.
  __builtin_amdgcn_global_load_lds((gas1_t)g, (las3_t)l, 16, 0, 0);
}

DEV f32x4 mfma16(short8 a, short8 b, f32x4 c) {
  return __builtin_amdgcn_mfma_f32_16x16x32_bf16(a, b, c, 0, 0, 0);
}

// ---------------- prep kernels ----------------

__global__ __launch_bounds__(256) void convert_x_kernel(const float* __restrict__ x,
                                                        unsigned short* __restrict__ xb) {
  size_t i = ((size_t)blockIdx.x * 256 + threadIdx.x) * 4;
  float4 v = *(const float4*)(x + i);
  unsigned long long pack = (unsigned long long)f2bf(v.x)
                          | ((unsigned long long)f2bf(v.y) << 16)
                          | ((unsigned long long)f2bf(v.z) << 32)
                          | ((unsigned long long)f2bf(v.w) << 48);
  *(unsigned long long*)(xb + i) = pack;
}

// src [K][N] fp32 -> dst [N][K] bf16 (LDS tiled transpose, 64x64 tiles)
__global__ __launch_bounds__(256) void transpose_w_kernel(const float* __restrict__ src,
                                                          unsigned short* __restrict__ dst,
                                                          int K, int N) {
  __shared__ float tile[64][65];
  const int k0 = blockIdx.x * 64, n0 = blockIdx.y * 64;
  for (int i = threadIdx.x; i < 4096; i += 256) {
    int r = i >> 6, c = i & 63;
    tile[r][c] = src[(size_t)(k0 + r) * N + n0 + c];
  }
  __syncthreads();
  for (int i = threadIdx.x; i < 4096; i += 256) {
    int r = i >> 6, c = i & 63;
    dst[(size_t)(n0 + r) * K + k0 + c] = f2bf(tile[c][r]);
  }
}

__global__ __launch_bounds__(256) void rope_table_kernel(float2* __restrict__ tab) {
  int t = blockIdx.x * 256 + threadIdx.x;        // S*64 = 131072
  int s = t >> 6, i = t & 63;
  float freq = powf(10000.0f, -(float)i * (1.0f / 64.0f));
  float ang = (float)s * freq;
  tab[t] = make_float2(cosf(ang), sinf(ang));
}

// QKV [4096][3072] bf16 -> Qb [B][H][S][hd] (rope, *1/sqrt(hd)), Kb [B][KV][S][hd] (rope)
__global__ __launch_bounds__(256) void rope_scatter_kernel(const unsigned short* __restrict__ QKV,
                                                           const float2* __restrict__ tab,
                                                           unsigned short* __restrict__ Qb,
                                                           unsigned short* __restrict__ Kb) {
  int t = blockIdx.x * 256 + threadIdx.x;
  const float qscale = 0.08838834764831845f;     // 1/sqrt(128)
  if (t < (1 << 22)) {                           // Q pairs: B*S*H*64 = 2^22
    int i = t & 63, h = (t >> 6) & 15, s = (t >> 10) & 2047, b = t >> 21;
    const unsigned short* p = QKV + (size_t)(b * NS + s) * NQKV + h * HD + 2 * i;
    float2 cs = tab[s * 64 + i];
    float x1 = bf2f(p[0]), x2 = bf2f(p[1]);
    unsigned short* q = Qb + (size_t)((b * NH + h) * NS + s) * HD + 2 * i;
    q[0] = f2bf((x1 * cs.x - x2 * cs.y) * qscale);
    q[1] = f2bf((x1 * cs.y + x2 * cs.x) * qscale);
  } else {                                       // K pairs: B*S*KV*64 = 2^20
    int u = t - (1 << 22);
    int i = u & 63, kv = (u >> 6) & 3, s = (u >> 8) & 2047, b = u >> 19;
    const unsigned short* p = QKV + (size_t)(b * NS + s) * NQKV + 2048 + kv * HD + 2 * i;
    float2 cs = tab[s * 64 + i];
    float x1 = bf2f(p[0]), x2 = bf2f(p[1]);
    unsigned short* k = Kb + (size_t)((b * NKV + kv) * NS + s) * HD + 2 * i;
    k[0] = f2bf(x1 * cs.x - x2 * cs.y);
    k[1] = f2bf(x1 * cs.y + x2 * cs.x);
  }
}

// V columns of QKV -> Vt [B][KV][hd][S] bf16 (transposed for PV B-fragments)
__global__ __launch_bounds__(256) void transpose_v_kernel(const unsigned short* __restrict__ QKV,
                                                          unsigned short* __restrict__ Vt) {
  __shared__ unsigned short tile[64][65];
  const int bk = blockIdx.x, b = bk >> 2, kv = bk & 3;
  const int s0 = blockIdx.y * 64, d0 = blockIdx.z * 64;
  for (int i = threadIdx.x; i < 4096; i += 256) {
    int r = i >> 6, c = i & 63;   // r = s-offset, c = d-offset
    tile[r][c] = QKV[(size_t)(b * NS + s0 + r) * NQKV + 2560 + kv * HD + d0 + c];
  }
  __syncthreads();
  for (int i = threadIdx.x; i < 4096; i += 256) {
    int r = i >> 6, c = i & 63;   // r = d-offset, c = s-offset
    Vt[(size_t)((b * NKV + kv) * HD + d0 + r) * NS + s0 + c] = tile[c][r];
  }
}

// ---------------- GEMM: C[M][N] = A[M][K=2048] * Bt[N][K]^T, bf16 in, acc fp32 ----------------
// 128x128 tile, BK=32, 4 waves (2x2), m97 structure (global_load_lds staging).

template <int N, bool OUTBF16>
__global__ __launch_bounds__(256) void gemm_kernel(const unsigned short* __restrict__ A,
                                                   const unsigned short* __restrict__ Bt,
                                                   void* __restrict__ Cout) {
  __shared__ unsigned short As[128 * 32];  // 8 KB
  __shared__ unsigned short Bs[128 * 32];
  const int K = 2048;
  const int tid = threadIdx.x, wid = tid >> 6, lane = tid & 63;
  const int wm = wid >> 1, wn = wid & 1;
  const int m0 = blockIdx.x * 128, n0 = blockIdx.y * 128;
  f32x4 acc[4][4] = {};
  const int srow = tid >> 2;           // 0..63
  const int scol = (tid & 3) * 8;
  const unsigned short* Ab = A + (size_t)(m0 + srow) * K + scol;
  const unsigned short* Ab2 = Ab + (size_t)64 * K;
  const unsigned short* Bb = Bt + (size_t)(n0 + srow) * K + scol;
  const unsigned short* Bb2 = Bb + (size_t)64 * K;

  for (int kt = 0; kt < K; kt += 32) {
    gload16(Ab + kt, &As[wid * 512]);
    gload16(Ab2 + kt, &As[2048 + wid * 512]);
    gload16(Bb + kt, &Bs[wid * 512]);
    gload16(Bb2 + kt, &Bs[2048 + wid * 512]);
    __syncthreads();                   // drains vmcnt before use
    short8 af[4], bfr[4];
#pragma unroll
    for (int r = 0; r < 4; ++r)
      af[r] = *(const short8*)&As[(wm * 64 + r * 16 + (lane & 15)) * 32 + (lane >> 4) * 8];
#pragma unroll
    for (int c = 0; c < 4; ++c)
      bfr[c] = *(const short8*)&Bs[(wn * 64 + c * 16 + (lane & 15)) * 32 + (lane >> 4) * 8];
#pragma unroll
    for (int r = 0; r < 4; ++r)
#pragma unroll
      for (int c = 0; c < 4; ++c)
        acc[r][c] = mfma16(af[r], bfr[c], acc[r][c]);
    __syncthreads();
  }

  // epilogue: C row = m0 + wm*64 + r*16 + (lane>>4)*4 + j ; col = n0 + wn*64 + c*16 + (lane&15)
  if (OUTBF16) {
    unsigned short* C = (unsigned short*)Cout;
#pragma unroll
    for (int r = 0; r < 4; ++r) {
      const int row = m0 + wm * 64 + r * 16 + (lane >> 4) * 4;
#pragma unroll
      for (int c = 0; c < 4; ++c) {
        const int col = n0 + wn * 64 + c * 16 + (lane & 15);
#pragma unroll
        for (int j = 0; j < 4; ++j)
          C[(size_t)(row + j) * N + col] = f2bf(acc[r][c][j]);
      }
    }
  } else {
    float* C = (float*)Cout;
#pragma unroll
    for (int r = 0; r < 4; ++r) {
      const int row = m0 + wm * 64 + r * 16 + (lane >> 4) * 4;
#pragma unroll
      for (int c = 0; c < 4; ++c) {
        const int col = n0 + wn * 64 + c * 16 + (lane & 15);
#pragma unroll
        for (int j = 0; j < 4; ++j)
          C[(size_t)(row + j) * N + col] = acc[r][c][j];
      }
    }
  }
}

// ---------------- flash attention (non-causal, GQA) ----------------
// grid = B*H*(S/64) = 1024 blocks; 4 waves, wave owns 16 q-rows; KVBLK=32.
// K tile [32][128] LDS, XOR-swizzle ((row&7)<<3) elems; V tile [128][32], ((row&3)<<3).
// Staged with global_load_lds + pre-swizzled SOURCE address (both-sides rule).

__global__ __launch_bounds__(256) void attn_kernel(const unsigned short* __restrict__ Qb,
                                                   const unsigned short* __restrict__ Kb,
                                                   const unsigned short* __restrict__ Vt,
                                                   unsigned short* __restrict__ O) {
  __shared__ unsigned short Ks[32 * 128];   // 8 KB
  __shared__ unsigned short Vs[128 * 32];   // 8 KB
  __shared__ unsigned short Ps[4][16 * 32]; // 4 KB, per-wave P bounce
  const int tid = threadIdx.x, wid = tid >> 6, lane = tid & 63;
  const int blk = blockIdx.x;
  const int qt = blk & 31, h = (blk >> 5) & 15, b = blk >> 9;
  const int kvh = h >> 2;
  const int q0 = qt * 64 + wid * 16;

  const unsigned short* qhead = Qb + (size_t)((b * NH + h) * NS) * HD;
  const unsigned short* khead = Kb + (size_t)((b * NKV + kvh) * NS) * HD;
  const unsigned short* vhead = Vt + (size_t)((b * NKV + kvh) * HD) * NS;

  short8 qf[4];
#pragma unroll
  for (int kk = 0; kk < 4; ++kk)
    qf[kk] = *(const short8*)(qhead + (size_t)(q0 + (lane & 15)) * HD + kk * 32 + (lane >> 4) * 8);

  f32x4 od[8] = {};
  float mrun[4], lpart[4];
#pragma unroll
  for (int j = 0; j < 4; ++j) { mrun[j] = -1e30f; lpart[j] = 0.0f; }

  // staging lane->source mapping (pre-swizzled so linear LDS == swizzled layout)
  const int krow0 = tid >> 4;            // K: rows 0..15 (+16 on issue 2), 128 elem rows
  const int kcolb = (tid & 15) * 8;
  const int vrow0 = tid >> 2;            // V: rows 0..63 (+64 on issue 2), 32 elem rows
  const int vcolb = (tid & 3) * 8;

  for (int kt = 0; kt < NS; kt += 32) {
    {
      int r0 = krow0,        c0 = kcolb ^ ((r0 & 7) << 3);
      int r1 = krow0 + 16,   c1 = kcolb ^ ((r1 & 7) << 3);
      gload16(khead + (size_t)(kt + r0) * HD + c0, &Ks[wid * 512]);
      gload16(khead + (size_t)(kt + r1) * HD + c1, &Ks[2048 + wid * 512]);
      int vr0 = vrow0,       vc0 = vcolb ^ ((vr0 & 3) << 3);
      int vr1 = vrow0 + 64,  vc1 = vcolb ^ ((vr1 & 3) << 3);
      gload16(vhead + (size_t)vr0 * NS + kt + vc0, &Vs[wid * 512]);
      gload16(vhead + (size_t)vr1 * NS + kt + vc1, &Vs[2048 + wid * 512]);
    }
    __syncthreads();

    // QK^T: scores 16x32 per wave (two 16x16 C-frags)
    f32x4 s0 = {0.f, 0.f, 0.f, 0.f}, s1 = {0.f, 0.f, 0.f, 0.f};
    {
      const int swk = (lane & 7) << 3;
#pragma unroll
      for (int kk = 0; kk < 4; ++kk) {
        short8 k0 = *(const short8*)&Ks[(((lane & 15) * 128) + kk * 32 + ((lane >> 4) * 8)) ^ swk];
        s0 = mfma16(qf[kk], k0, s0);
      }
#pragma unroll
      for (int kk = 0; kk < 4; ++kk) {
        short8 k1 = *(const short8*)&Ks[((((lane & 15) + 16) * 128) + kk * 32 + ((lane >> 4) * 8)) ^ swk];
        s1 = mfma16(qf[kk], k1, s1);
      }
    }

    // online softmax (rows live in 16-lane groups: row = (lane>>4)*4 + j, col = lane&15)
    float corr[4];
#pragma unroll
    for (int j = 0; j < 4; ++j) {
      float mt = fmaxf(s0[j], s1[j]);
#pragma unroll
      for (int msk = 1; msk <= 8; msk <<= 1)
        mt = fmaxf(mt, __shfl_xor(mt, msk, 64));
      float mn = fmaxf(mrun[j], mt);
      corr[j] = __expf(mrun[j] - mn);
      mrun[j] = mn;
      float p0 = __expf(s0[j] - mn);
      float p1 = __expf(s1[j] - mn);
      lpart[j] = lpart[j] * corr[j] + p0 + p1;
      s0[j] = p0; s1[j] = p1;
    }
#pragma unroll
    for (int c = 0; c < 8; ++c)
#pragma unroll
      for (int j = 0; j < 4; ++j)
        od[c][j] *= corr[j];

    // P (16x32) -> LDS bf16 (swizzled (row&3)<<3), then re-read as A-fragment
    {
      unsigned short* pw = &Ps[wid][0];
      const int g4 = (lane >> 4) * 4, cl = lane & 15;
#pragma unroll
      for (int j = 0; j < 4; ++j) {
        const int row = g4 + j;
        const int sw = (row & 3) << 3;
        pw[((row * 32) + cl) ^ sw] = f2bf(s0[j]);
        pw[((row * 32) + 16 + cl) ^ sw] = f2bf(s1[j]);
      }
    }
    asm volatile("s_waitcnt lgkmcnt(0)" ::: "memory");
    __builtin_amdgcn_sched_barrier(0);
    short8 pa = *(const short8*)&Ps[wid][(((lane & 15) * 32) + ((lane >> 4) * 8)) ^ ((lane & 3) << 3)];

    // PV: od[c] += P(16x32) @ V(32x16) per d-chunk c
    {
      const int swv = (lane & 3) << 3;
#pragma unroll
      for (int c = 0; c < 8; ++c) {
        short8 vf = *(const short8*)&Vs[(((c * 16 + (lane & 15)) * 32) + ((lane >> 4) * 8)) ^ swv];
        od[c] = mfma16(pa, vf, od[c]);
      }
    }
    __syncthreads();  // all waves done with Ks/Vs before next stage
  }

  // finalize: row sums + write O[B*S][H*hd] bf16
  float linv[4];
#pragma unroll
  for (int j = 0; j < 4; ++j) {
    float l = lpart[j];
#pragma unroll
    for (int msk = 1; msk <= 8; msk <<= 1)
      l += __shfl_xor(l, msk, 64);
    linv[j] = 1.0f / l;
  }
  const int orow0 = b * NS + q0 + (lane >> 4) * 4;
#pragma unroll
  for (int c = 0; c < 8; ++c)
#pragma unroll
    for (int j = 0; j < 4; ++j)
      O[(size_t)(orow0 + j) * ND + h * HD + c * 16 + (lane & 15)] = f2bf(od[c][j] * linv[j]);
}

// ---------------- launch ----------------

extern "C" void kernel_launch(void* const* d_in, const int* in_sizes, int n_in,
                              void* d_out, int out_size, void* d_ws, size_t ws_size,
                              hipStream_t stream) {
  const float* x  = (const float*)d_in[0];
  const float* wq = (const float*)d_in[1];
  const float* wk = (const float*)d_in[2];
  const float* wv = (const float*)d_in[3];
  const float* wo = (const float*)d_in[4];
  float* out = (float*)d_out;
  char* ws = (char*)d_ws;

  // ws layout (bytes); total needed = 63,963,136
  unsigned short* xb   = (unsigned short*)(ws + 0);          // 16.8 MB [4096][2048] bf16
  unsigned short* wT   = (unsigned short*)(ws + 16777216);   // 12.6 MB [3072][2048] bf16 (wq|wk|wv)^T
  unsigned short* woT  = (unsigned short*)(ws + 29360128);   //  8.4 MB [2048][2048] bf16
  float2*         tab  = (float2*)(ws + 37748736);           //  1.0 MB [2048][64] cos/sin
  unsigned short* QKV  = (unsigned short*)(ws + 38797312);   // 25.2 MB [4096][3072] bf16
  unsigned short* Qb   = xb;                                 // alias: xb dead after GEMM1
  unsigned short* Kb   = wT;                                 // alias: wT dead after GEMM1
  unsigned short* Vt   = (unsigned short*)(ws + 16777216 + 4194304);
  unsigned short* Obuf = QKV;                                // alias: QKV dead after scatter

  convert_x_kernel<<<8192, 256, 0, stream>>>(x, xb);
  transpose_w_kernel<<<dim3(32, 32), 256, 0, stream>>>(wq, wT, 2048, 2048);
  transpose_w_kernel<<<dim3(32, 8),  256, 0, stream>>>(wk, wT + (size_t)2048 * 2048, 2048, 512);
  transpose_w_kernel<<<dim3(32, 8),  256, 0, stream>>>(wv, wT + (size_t)2560 * 2048, 2048, 512);
  transpose_w_kernel<<<dim3(32, 32), 256, 0, stream>>>(wo, woT, 2048, 2048);
  rope_table_kernel<<<512, 256, 0, stream>>>(tab);

  gemm_kernel<NQKV, true><<<dim3(32, 24), 256, 0, stream>>>(xb, wT, QKV);

  rope_scatter_kernel<<<20480, 256, 0, stream>>>(QKV, tab, Qb, Kb);
  transpose_v_kernel<<<dim3(8, 32, 2), 256, 0, stream>>>(QKV, Vt);

  attn_kernel<<<1024, 256, 0, stream>>>(Qb, Kb, Vt, Obuf);

  gemm_kernel<ND, false><<<dim3(32, 16), 256, 0, stream>>>(Obuf, woT, out);
}

// Round 2
// 301.569 us; speedup vs baseline: 1.1441x; 1.1441x over previous
//
#include <hip/hip_runtime.h>

// ---------------------------------------------------------------------------
// MHA (GQA + RoPE, non-causal) on MI355X, bf16 MFMA pipeline, fp32 in/out.
// B=2 S=2048 D=2048 H=16 KV=4 hd=128.
// R2: attention KVBLK 32->64, defer-max rescale (T13), exp2-based softmax,
//     cheap bf16 pack, setprio around MFMA clusters.
// ---------------------------------------------------------------------------

typedef __attribute__((ext_vector_type(8))) short short8;
typedef __attribute__((ext_vector_type(4))) float f32x4;

#define DEV static __device__ __forceinline__

#define NB 2
#define NS 2048
#define ND 2048
#define NH 16
#define NKV 4
#define HD 128
#define NQKV 3072   // H*hd + 2*KV*hd

DEV unsigned short f2bf(float f) {
  union { float f; unsigned u; } v; v.f = f;
  unsigned r = v.u + 0x7fffu + ((v.u >> 16) & 1u);   // RNE
  return (unsigned short)(r >> 16);
}
DEV unsigned short f2bf_fast(float f) {            // round-to-nearest (cheap)
  union { float f; unsigned u; } v; v.f = f;
  return (unsigned short)((v.u + 0x8000u) >> 16);
}
DEV float bf2f(unsigned short u) {
  union { unsigned u; float f; } v; v.u = ((unsigned)u) << 16; return v.f;
}

typedef const __attribute__((address_space(1))) void* gas1_t;
typedef __attribute__((address_space(3))) void* las3_t;
DEV void gload16(const void* g, void* l) {
  // global -> LDS direct, 16B/lane; LDS dest = wave-uniform base + lane*16.
  __builtin_amdgcn_global_load_lds((gas1_t)g, (las3_t)l, 16, 0, 0);
}

DEV f32x4 mfma16(short8 a, short8 b, f32x4 c) {
  return __builtin_amdgcn_mfma_f32_16x16x32_bf16(a, b, c, 0, 0, 0);
}

// ---------------- prep kernels ----------------

__global__ __launch_bounds__(256) void convert_x_kernel(const float* __restrict__ x,
                                                        unsigned short* __restrict__ xb) {
  size_t i = ((size_t)blockIdx.x * 256 + threadIdx.x) * 4;
  float4 v = *(const float4*)(x + i);
  unsigned long long pack = (unsigned long long)f2bf(v.x)
                          | ((unsigned long long)f2bf(v.y) << 16)
                          | ((unsigned long long)f2bf(v.z) << 32)
                          | ((unsigned long long)f2bf(v.w) << 48);
  *(unsigned long long*)(xb + i) = pack;
}

// src [K][N] fp32 -> dst [N][K] bf16 (LDS tiled transpose, 64x64 tiles)
__global__ __launch_bounds__(256) void transpose_w_kernel(const float* __restrict__ src,
                                                          unsigned short* __restrict__ dst,
                                                          int K, int N) {
  __shared__ float tile[64][65];
  const int k0 = blockIdx.x * 64, n0 = blockIdx.y * 64;
  for (int i = threadIdx.x; i < 4096; i += 256) {
    int r = i >> 6, c = i & 63;
    tile[r][c] = src[(size_t)(k0 + r) * N + n0 + c];
  }
  __syncthreads();
  for (int i = threadIdx.x; i < 4096; i += 256) {
    int r = i >> 6, c = i & 63;
    dst[(size_t)(n0 + r) * K + k0 + c] = f2bf(tile[c][r]);
  }
}

__global__ __launch_bounds__(256) void rope_table_kernel(float2* __restrict__ tab) {
  int t = blockIdx.x * 256 + threadIdx.x;        // S*64 = 131072
  int s = t >> 6, i = t & 63;
  float freq = powf(10000.0f, -(float)i * (1.0f / 64.0f));
  float ang = (float)s * freq;
  tab[t] = make_float2(cosf(ang), sinf(ang));
}

// QKV [4096][3072] bf16 -> Qb [B][H][S][hd] (rope, *log2e/sqrt(hd)), Kb (rope)
__global__ __launch_bounds__(256) void rope_scatter_kernel(const unsigned short* __restrict__ QKV,
                                                           const float2* __restrict__ tab,
                                                           unsigned short* __restrict__ Qb,
                                                           unsigned short* __restrict__ Kb) {
  int t = blockIdx.x * 256 + threadIdx.x;
  const float qscale = 0.12751741161895452f;     // (1/sqrt(128)) * log2(e)
  if (t < (1 << 22)) {                           // Q pairs: B*S*H*64 = 2^22
    int i = t & 63, h = (t >> 6) & 15, s = (t >> 10) & 2047, b = t >> 21;
    const unsigned short* p = QKV + (size_t)(b * NS + s) * NQKV + h * HD + 2 * i;
    float2 cs = tab[s * 64 + i];
    float x1 = bf2f(p[0]), x2 = bf2f(p[1]);
    unsigned short* q = Qb + (size_t)((b * NH + h) * NS + s) * HD + 2 * i;
    q[0] = f2bf((x1 * cs.x - x2 * cs.y) * qscale);
    q[1] = f2bf((x1 * cs.y + x2 * cs.x) * qscale);
  } else {                                       // K pairs: B*S*KV*64 = 2^20
    int u = t - (1 << 22);
    int i = u & 63, kv = (u >> 6) & 3, s = (u >> 8) & 2047, b = u >> 19;
    const unsigned short* p = QKV + (size_t)(b * NS + s) * NQKV + 2048 + kv * HD + 2 * i;
    float2 cs = tab[s * 64 + i];
    float x1 = bf2f(p[0]), x2 = bf2f(p[1]);
    unsigned short* k = Kb + (size_t)((b * NKV + kv) * NS + s) * HD + 2 * i;
    k[0] = f2bf(x1 * cs.x - x2 * cs.y);
    k[1] = f2bf(x1 * cs.y + x2 * cs.x);
  }
}

// V columns of QKV -> Vt [B][KV][hd][S] bf16 (transposed for PV B-fragments)
__global__ __launch_bounds__(256) void transpose_v_kernel(const unsigned short* __restrict__ QKV,
                                                          unsigned short* __restrict__ Vt) {
  __shared__ unsigned short tile[64][65];
  const int bk = blockIdx.x, b = bk >> 2, kv = bk & 3;
  const int s0 = blockIdx.y * 64, d0 = blockIdx.z * 64;
  for (int i = threadIdx.x; i < 4096; i += 256) {
    int r = i >> 6, c = i & 63;   // r = s-offset, c = d-offset
    tile[r][c] = QKV[(size_t)(b * NS + s0 + r) * NQKV + 2560 + kv * HD + d0 + c];
  }
  __syncthreads();
  for (int i = threadIdx.x; i < 4096; i += 256) {
    int r = i >> 6, c = i & 63;   // r = d-offset, c = s-offset
    Vt[(size_t)((b * NKV + kv) * HD + d0 + r) * NS + s0 + c] = tile[c][r];
  }
}

// ---------------- GEMM: C[M][N] = A[M][K=2048] * Bt[N][K]^T, bf16 in, acc fp32 ----------------
// 128x128 tile, BK=32, 4 waves (2x2), m97 structure (global_load_lds staging).

template <int N, bool OUTBF16>
__global__ __launch_bounds__(256) void gemm_kernel(const unsigned short* __restrict__ A,
                                                   const unsigned short* __restrict__ Bt,
                                                   void* __restrict__ Cout) {
  __shared__ unsigned short As[128 * 32];  // 8 KB
  __shared__ unsigned short Bs[128 * 32];
  const int K = 2048;
  const int tid = threadIdx.x, wid = tid >> 6, lane = tid & 63;
  const int wm = wid >> 1, wn = wid & 1;
  const int m0 = blockIdx.x * 128, n0 = blockIdx.y * 128;
  f32x4 acc[4][4] = {};
  const int srow = tid >> 2;           // 0..63
  const int scol = (tid & 3) * 8;
  const unsigned short* Ab = A + (size_t)(m0 + srow) * K + scol;
  const unsigned short* Ab2 = Ab + (size_t)64 * K;
  const unsigned short* Bb = Bt + (size_t)(n0 + srow) * K + scol;
  const unsigned short* Bb2 = Bb + (size_t)64 * K;

  for (int kt = 0; kt < K; kt += 32) {
    gload16(Ab + kt, &As[wid * 512]);
    gload16(Ab2 + kt, &As[2048 + wid * 512]);
    gload16(Bb + kt, &Bs[wid * 512]);
    gload16(Bb2 + kt, &Bs[2048 + wid * 512]);
    __syncthreads();                   // drains vmcnt before use
    short8 af[4], bfr[4];
#pragma unroll
    for (int r = 0; r < 4; ++r)
      af[r] = *(const short8*)&As[(wm * 64 + r * 16 + (lane & 15)) * 32 + (lane >> 4) * 8];
#pragma unroll
    for (int c = 0; c < 4; ++c)
      bfr[c] = *(const short8*)&Bs[(wn * 64 + c * 16 + (lane & 15)) * 32 + (lane >> 4) * 8];
    __builtin_amdgcn_s_setprio(1);
#pragma unroll
    for (int r = 0; r < 4; ++r)
#pragma unroll
      for (int c = 0; c < 4; ++c)
        acc[r][c] = mfma16(af[r], bfr[c], acc[r][c]);
    __builtin_amdgcn_s_setprio(0);
    __syncthreads();
  }

  // epilogue: C row = m0 + wm*64 + r*16 + (lane>>4)*4 + j ; col = n0 + wn*64 + c*16 + (lane&15)
  if (OUTBF16) {
    unsigned short* C = (unsigned short*)Cout;
#pragma unroll
    for (int r = 0; r < 4; ++r) {
      const int row = m0 + wm * 64 + r * 16 + (lane >> 4) * 4;
#pragma unroll
      for (int c = 0; c < 4; ++c) {
        const int col = n0 + wn * 64 + c * 16 + (lane & 15);
#pragma unroll
        for (int j = 0; j < 4; ++j)
          C[(size_t)(row + j) * N + col] = f2bf(acc[r][c][j]);
      }
    }
  } else {
    float* C = (float*)Cout;
#pragma unroll
    for (int r = 0; r < 4; ++r) {
      const int row = m0 + wm * 64 + r * 16 + (lane >> 4) * 4;
#pragma unroll
      for (int c = 0; c < 4; ++c) {
        const int col = n0 + wn * 64 + c * 16 + (lane & 15);
#pragma unroll
        for (int j = 0; j < 4; ++j)
          C[(size_t)(row + j) * N + col] = acc[r][c][j];
      }
    }
  }
}

// ---------------- flash attention (non-causal, GQA) ----------------
// grid = B*H*(S/64) = 1024 blocks; 4 waves, wave owns 16 q-rows; KVBLK=64.
// LDS: K [64][128] swz ((row&7)<<3), V [128][64] swz ((row&7)<<3),
//      P per-wave [16][64] swz ((row&7)<<3). 40 KB total.
// Scores are in log2 units (Q pre-scaled by log2e/sqrt(hd)); softmax = exp2.
// Defer-max (T13): skip od-rescale unless a row max grows past THR=8.

__global__ __launch_bounds__(256) void attn_kernel(const unsigned short* __restrict__ Qb,
                                                   const unsigned short* __restrict__ Kb,
                                                   const unsigned short* __restrict__ Vt,
                                                   unsigned short* __restrict__ O) {
  __shared__ unsigned short Ks[64 * 128];   // 16 KB
  __shared__ unsigned short Vs[128 * 64];   // 16 KB
  __shared__ unsigned short Ps[4][16 * 64]; //  8 KB, per-wave P bounce
  const int tid = threadIdx.x, wid = tid >> 6, lane = tid & 63;
  const int blk = blockIdx.x;
  const int qt = blk & 31, h = (blk >> 5) & 15, b = blk >> 9;
  const int kvh = h >> 2;
  const int q0 = qt * 64 + wid * 16;

  const unsigned short* qhead = Qb + (size_t)((b * NH + h) * NS) * HD;
  const unsigned short* khead = Kb + (size_t)((b * NKV + kvh) * NS) * HD;
  const unsigned short* vhead = Vt + (size_t)((b * NKV + kvh) * HD) * NS;

  short8 qf[4];
#pragma unroll
  for (int kk = 0; kk < 4; ++kk)
    qf[kk] = *(const short8*)(qhead + (size_t)(q0 + (lane & 15)) * HD + kk * 32 + (lane >> 4) * 8);

  f32x4 od[8] = {};
  float mrun[4], lpart[4];
#pragma unroll
  for (int j = 0; j < 4; ++j) { mrun[j] = -1e30f; lpart[j] = 0.0f; }

  const int swk = (lane & 7) << 3;          // read-side swizzle (row&7 == lane&7 for all tiles)
  const int g4 = (lane >> 4) * 4, cl = lane & 15;

  for (int kt = 0; kt < NS; kt += 64) {
    // ---- stage K (64x128) and V (128x64) via global_load_lds, pre-swizzled source ----
#pragma unroll
    for (int i = 0; i < 4; ++i) {
      int row = i * 16 + (tid >> 4);
      int col = ((tid & 15) * 8) ^ ((row & 7) << 3);
      gload16(khead + (size_t)(kt + row) * HD + col, &Ks[i * 2048 + wid * 512]);
    }
#pragma unroll
    for (int i = 0; i < 4; ++i) {
      int row = i * 32 + (tid >> 3);
      int col = ((tid & 7) * 8) ^ ((row & 7) << 3);
      gload16(vhead + (size_t)row * NS + kt + col, &Vs[i * 2048 + wid * 512]);
    }
    __syncthreads();

    // ---- QK^T: 16x64 scores per wave (4 col-frags x 4 k-slices) ----
    f32x4 s[4];
    __builtin_amdgcn_s_setprio(1);
#pragma unroll
    for (int c4 = 0; c4 < 4; ++c4) {
      s[c4] = f32x4{0.f, 0.f, 0.f, 0.f};
#pragma unroll
      for (int kk = 0; kk < 4; ++kk) {
        short8 kf = *(const short8*)&Ks[((c4 * 16 + cl) * 128 + kk * 32 + (lane >> 4) * 8) ^ swk];
        s[c4] = mfma16(qf[kk], kf, s[c4]);
      }
    }
    __builtin_amdgcn_s_setprio(0);

    // ---- online softmax (log2 domain), defer-max ----
    float mt4[4];
#pragma unroll
    for (int j = 0; j < 4; ++j) {
      float m = fmaxf(fmaxf(s[0][j], s[1][j]), fmaxf(s[2][j], s[3][j]));
#pragma unroll
      for (int msk = 1; msk <= 8; msk <<= 1)
        m = fmaxf(m, __shfl_xor(m, msk, 64));
      mt4[j] = m;
    }
    bool need = (mt4[0] > mrun[0] + 8.0f) || (mt4[1] > mrun[1] + 8.0f) ||
                (mt4[2] > mrun[2] + 8.0f) || (mt4[3] > mrun[3] + 8.0f);
    if (__any(need)) {
#pragma unroll
      for (int j = 0; j < 4; ++j) {
        float mn = fmaxf(mrun[j], mt4[j]);
        float corr = __builtin_amdgcn_exp2f(mrun[j] - mn);
        mrun[j] = mn;
        lpart[j] *= corr;
#pragma unroll
        for (int c = 0; c < 8; ++c)
          od[c][j] *= corr;
      }
    }
#pragma unroll
    for (int j = 0; j < 4; ++j) {
      float acc = 0.f;
#pragma unroll
      for (int c4 = 0; c4 < 4; ++c4) {
        float p = __builtin_amdgcn_exp2f(s[c4][j] - mrun[j]);
        s[c4][j] = p;
        acc += p;
      }
      lpart[j] += acc;
    }

    // ---- P (16x64) -> LDS bf16, swizzled; re-read as PV A-fragments ----
    {
      unsigned short* pw = &Ps[wid][0];
#pragma unroll
      for (int j = 0; j < 4; ++j) {
        const int row = g4 + j;
        const int sw = (row & 7) << 3;
#pragma unroll
        for (int c4 = 0; c4 < 4; ++c4)
          pw[(row * 64 + c4 * 16 + cl) ^ sw] = f2bf_fast(s[c4][j]);
      }
    }
    asm volatile("s_waitcnt lgkmcnt(0)" ::: "memory");
    __builtin_amdgcn_sched_barrier(0);
    short8 pa0 = *(const short8*)&Ps[wid][(cl * 64 + (lane >> 4) * 8) ^ swk];
    short8 pa1 = *(const short8*)&Ps[wid][(cl * 64 + 32 + (lane >> 4) * 8) ^ swk];

    // ---- PV: od[c] += P(16x64) @ V(64x16) per d-chunk c ----
    __builtin_amdgcn_s_setprio(1);
#pragma unroll
    for (int c = 0; c < 8; ++c) {
      const int r = c * 16 + cl;   // d-row in Vs
      short8 vf0 = *(const short8*)&Vs[(r * 64 + (lane >> 4) * 8) ^ swk];
      short8 vf1 = *(const short8*)&Vs[(r * 64 + 32 + (lane >> 4) * 8) ^ swk];
      od[c] = mfma16(pa0, vf0, od[c]);
      od[c] = mfma16(pa1, vf1, od[c]);
    }
    __builtin_amdgcn_s_setprio(0);
    __syncthreads();  // all waves done with Ks/Vs before next stage
  }

  // ---- finalize: row sums + write O[B*S][H*hd] bf16 ----
  float linv[4];
#pragma unroll
  for (int j = 0; j < 4; ++j) {
    float l = lpart[j];
#pragma unroll
    for (int msk = 1; msk <= 8; msk <<= 1)
      l += __shfl_xor(l, msk, 64);
    linv[j] = 1.0f / l;
  }
  const int orow0 = b * NS + q0 + g4;
#pragma unroll
  for (int c = 0; c < 8; ++c)
#pragma unroll
    for (int j = 0; j < 4; ++j)
      O[(size_t)(orow0 + j) * ND + h * HD + c * 16 + cl] = f2bf(od[c][j] * linv[j]);
}

// ---------------- launch ----------------

extern "C" void kernel_launch(void* const* d_in, const int* in_sizes, int n_in,
                              void* d_out, int out_size, void* d_ws, size_t ws_size,
                              hipStream_t stream) {
  const float* x  = (const float*)d_in[0];
  const float* wq = (const float*)d_in[1];
  const float* wk = (const float*)d_in[2];
  const float* wv = (const float*)d_in[3];
  const float* wo = (const float*)d_in[4];
  float* out = (float*)d_out;
  char* ws = (char*)d_ws;

  // ws layout (bytes); total needed = 63,963,136
  unsigned short* xb   = (unsigned short*)(ws + 0);          // 16.8 MB [4096][2048] bf16
  unsigned short* wT   = (unsigned short*)(ws + 16777216);   // 12.6 MB [3072][2048] bf16 (wq|wk|wv)^T
  unsigned short* woT  = (unsigned short*)(ws + 29360128);   //  8.4 MB [2048][2048] bf16
  float2*         tab  = (float2*)(ws + 37748736);           //  1.0 MB [2048][64] cos/sin
  unsigned short* QKV  = (unsigned short*)(ws + 38797312);   // 25.2 MB [4096][3072] bf16
  unsigned short* Qb   = xb;                                 // alias: xb dead after GEMM1
  unsigned short* Kb   = wT;                                 // alias: wT dead after GEMM1
  unsigned short* Vt   = (unsigned short*)(ws + 16777216 + 4194304);
  unsigned short* Obuf = QKV;                                // alias: QKV dead after scatter

  convert_x_kernel<<<8192, 256, 0, stream>>>(x, xb);
  transpose_w_kernel<<<dim3(32, 32), 256, 0, stream>>>(wq, wT, 2048, 2048);
  transpose_w_kernel<<<dim3(32, 8),  256, 0, stream>>>(wk, wT + (size_t)2048 * 2048, 2048, 512);
  transpose_w_kernel<<<dim3(32, 8),  256, 0, stream>>>(wv, wT + (size_t)2560 * 2048, 2048, 512);
  transpose_w_kernel<<<dim3(32, 32), 256, 0, stream>>>(wo, woT, 2048, 2048);
  rope_table_kernel<<<512, 256, 0, stream>>>(tab);

  gemm_kernel<NQKV, true><<<dim3(32, 24), 256, 0, stream>>>(xb, wT, QKV);

  rope_scatter_kernel<<<20480, 256, 0, stream>>>(QKV, tab, Qb, Kb);
  transpose_v_kernel<<<dim3(8, 32, 2), 256, 0, stream>>>(QKV, Vt);

  attn_kernel<<<1024, 256, 0, stream>>>(Qb, Kb, Vt, Obuf);

  gemm_kernel<ND, false><<<dim3(32, 16), 256, 0, stream>>>(Obuf, woT, out);
}

// Round 3
// 269.632 us; speedup vs baseline: 1.2796x; 1.1184x over previous
//
#include <hip/hip_runtime.h>

// ---------------------------------------------------------------------------
// MHA (GQA + RoPE, non-causal) on MI355X, bf16 MFMA pipeline, fp32 in/out.
// B=2 S=2048 D=2048 H=16 KV=4 hd=128.
// R3: attention double-buffered K/V with counted vmcnt prefetch (T3-min),
//     32 q-rows/wave (2 row frags), raw s_barrier schedule.
// ---------------------------------------------------------------------------

typedef __attribute__((ext_vector_type(8))) short short8;
typedef __attribute__((ext_vector_type(4))) float f32x4;

#define DEV static __device__ __forceinline__

#define NB 2
#define NS 2048
#define ND 2048
#define NH 16
#define NKV 4
#define HD 128
#define NQKV 3072   // H*hd + 2*KV*hd

DEV unsigned short f2bf(float f) {
  union { float f; unsigned u; } v; v.f = f;
  unsigned r = v.u + 0x7fffu + ((v.u >> 16) & 1u);   // RNE
  return (unsigned short)(r >> 16);
}
DEV unsigned short f2bf_fast(float f) {            // round-to-nearest (cheap)
  union { float f; unsigned u; } v; v.f = f;
  return (unsigned short)((v.u + 0x8000u) >> 16);
}
DEV float bf2f(unsigned short u) {
  union { unsigned u; float f; } v; v.u = ((unsigned)u) << 16; return v.f;
}

typedef const __attribute__((address_space(1))) void* gas1_t;
typedef __attribute__((address_space(3))) void* las3_t;
DEV void gload16(const void* g, void* l) {
  // global -> LDS direct, 16B/lane; LDS dest = wave-uniform base + lane*16.
  __builtin_amdgcn_global_load_lds((gas1_t)g, (las3_t)l, 16, 0, 0);
}

DEV f32x4 mfma16(short8 a, short8 b, f32x4 c) {
  return __builtin_amdgcn_mfma_f32_16x16x32_bf16(a, b, c, 0, 0, 0);
}

// ---------------- prep kernels ----------------

__global__ __launch_bounds__(256) void convert_x_kernel(const float* __restrict__ x,
                                                        unsigned short* __restrict__ xb) {
  size_t i = ((size_t)blockIdx.x * 256 + threadIdx.x) * 4;
  float4 v = *(const float4*)(x + i);
  unsigned long long pack = (unsigned long long)f2bf(v.x)
                          | ((unsigned long long)f2bf(v.y) << 16)
                          | ((unsigned long long)f2bf(v.z) << 32)
                          | ((unsigned long long)f2bf(v.w) << 48);
  *(unsigned long long*)(xb + i) = pack;
}

// src [K][N] fp32 -> dst [N][K] bf16 (LDS tiled transpose, 64x64 tiles)
__global__ __launch_bounds__(256) void transpose_w_kernel(const float* __restrict__ src,
                                                          unsigned short* __restrict__ dst,
                                                          int K, int N) {
  __shared__ float tile[64][65];
  const int k0 = blockIdx.x * 64, n0 = blockIdx.y * 64;
  for (int i = threadIdx.x; i < 4096; i += 256) {
    int r = i >> 6, c = i & 63;
    tile[r][c] = src[(size_t)(k0 + r) * N + n0 + c];
  }
  __syncthreads();
  for (int i = threadIdx.x; i < 4096; i += 256) {
    int r = i >> 6, c = i & 63;
    dst[(size_t)(n0 + r) * K + k0 + c] = f2bf(tile[c][r]);
  }
}

__global__ __launch_bounds__(256) void rope_table_kernel(float2* __restrict__ tab) {
  int t = blockIdx.x * 256 + threadIdx.x;        // S*64 = 131072
  int s = t >> 6, i = t & 63;
  float freq = powf(10000.0f, -(float)i * (1.0f / 64.0f));
  float ang = (float)s * freq;
  tab[t] = make_float2(cosf(ang), sinf(ang));
}

// QKV [4096][3072] bf16 -> Qb [B][H][S][hd] (rope, *log2e/sqrt(hd)), Kb (rope)
__global__ __launch_bounds__(256) void rope_scatter_kernel(const unsigned short* __restrict__ QKV,
                                                           const float2* __restrict__ tab,
                                                           unsigned short* __restrict__ Qb,
                                                           unsigned short* __restrict__ Kb) {
  int t = blockIdx.x * 256 + threadIdx.x;
  const float qscale = 0.12751741161895452f;     // (1/sqrt(128)) * log2(e)
  if (t < (1 << 22)) {                           // Q pairs: B*S*H*64 = 2^22
    int i = t & 63, h = (t >> 6) & 15, s = (t >> 10) & 2047, b = t >> 21;
    const unsigned short* p = QKV + (size_t)(b * NS + s) * NQKV + h * HD + 2 * i;
    float2 cs = tab[s * 64 + i];
    float x1 = bf2f(p[0]), x2 = bf2f(p[1]);
    unsigned short* q = Qb + (size_t)((b * NH + h) * NS + s) * HD + 2 * i;
    q[0] = f2bf((x1 * cs.x - x2 * cs.y) * qscale);
    q[1] = f2bf((x1 * cs.y + x2 * cs.x) * qscale);
  } else {                                       // K pairs: B*S*KV*64 = 2^20
    int u = t - (1 << 22);
    int i = u & 63, kv = (u >> 6) & 3, s = (u >> 8) & 2047, b = u >> 19;
    const unsigned short* p = QKV + (size_t)(b * NS + s) * NQKV + 2048 + kv * HD + 2 * i;
    float2 cs = tab[s * 64 + i];
    float x1 = bf2f(p[0]), x2 = bf2f(p[1]);
    unsigned short* k = Kb + (size_t)((b * NKV + kv) * NS + s) * HD + 2 * i;
    k[0] = f2bf(x1 * cs.x - x2 * cs.y);
    k[1] = f2bf(x1 * cs.y + x2 * cs.x);
  }
}

// V columns of QKV -> Vt [B][KV][hd][S] bf16 (transposed for PV B-fragments)
__global__ __launch_bounds__(256) void transpose_v_kernel(const unsigned short* __restrict__ QKV,
                                                          unsigned short* __restrict__ Vt) {
  __shared__ unsigned short tile[64][65];
  const int bk = blockIdx.x, b = bk >> 2, kv = bk & 3;
  const int s0 = blockIdx.y * 64, d0 = blockIdx.z * 64;
  for (int i = threadIdx.x; i < 4096; i += 256) {
    int r = i >> 6, c = i & 63;   // r = s-offset, c = d-offset
    tile[r][c] = QKV[(size_t)(b * NS + s0 + r) * NQKV + 2560 + kv * HD + d0 + c];
  }
  __syncthreads();
  for (int i = threadIdx.x; i < 4096; i += 256) {
    int r = i >> 6, c = i & 63;   // r = d-offset, c = s-offset
    Vt[(size_t)((b * NKV + kv) * HD + d0 + r) * NS + s0 + c] = tile[c][r];
  }
}

// ---------------- GEMM: C[M][N] = A[M][K=2048] * Bt[N][K]^T, bf16 in, acc fp32 ----------------
// 128x128 tile, BK=32, 4 waves (2x2), m97 structure (global_load_lds staging).

template <int N, bool OUTBF16>
__global__ __launch_bounds__(256) void gemm_kernel(const unsigned short* __restrict__ A,
                                                   const unsigned short* __restrict__ Bt,
                                                   void* __restrict__ Cout) {
  __shared__ unsigned short As[128 * 32];  // 8 KB
  __shared__ unsigned short Bs[128 * 32];
  const int K = 2048;
  const int tid = threadIdx.x, wid = tid >> 6, lane = tid & 63;
  const int wm = wid >> 1, wn = wid & 1;
  const int m0 = blockIdx.x * 128, n0 = blockIdx.y * 128;
  f32x4 acc[4][4] = {};
  const int srow = tid >> 2;           // 0..63
  const int scol = (tid & 3) * 8;
  const unsigned short* Ab = A + (size_t)(m0 + srow) * K + scol;
  const unsigned short* Ab2 = Ab + (size_t)64 * K;
  const unsigned short* Bb = Bt + (size_t)(n0 + srow) * K + scol;
  const unsigned short* Bb2 = Bb + (size_t)64 * K;

  for (int kt = 0; kt < K; kt += 32) {
    gload16(Ab + kt, &As[wid * 512]);
    gload16(Ab2 + kt, &As[2048 + wid * 512]);
    gload16(Bb + kt, &Bs[wid * 512]);
    gload16(Bb2 + kt, &Bs[2048 + wid * 512]);
    __syncthreads();                   // drains vmcnt before use
    short8 af[4], bfr[4];
#pragma unroll
    for (int r = 0; r < 4; ++r)
      af[r] = *(const short8*)&As[(wm * 64 + r * 16 + (lane & 15)) * 32 + (lane >> 4) * 8];
#pragma unroll
    for (int c = 0; c < 4; ++c)
      bfr[c] = *(const short8*)&Bs[(wn * 64 + c * 16 + (lane & 15)) * 32 + (lane >> 4) * 8];
    __builtin_amdgcn_s_setprio(1);
#pragma unroll
    for (int r = 0; r < 4; ++r)
#pragma unroll
      for (int c = 0; c < 4; ++c)
        acc[r][c] = mfma16(af[r], bfr[c], acc[r][c]);
    __builtin_amdgcn_s_setprio(0);
    __syncthreads();
  }

  // epilogue: C row = m0 + wm*64 + r*16 + (lane>>4)*4 + j ; col = n0 + wn*64 + c*16 + (lane&15)
  if (OUTBF16) {
    unsigned short* C = (unsigned short*)Cout;
#pragma unroll
    for (int r = 0; r < 4; ++r) {
      const int row = m0 + wm * 64 + r * 16 + (lane >> 4) * 4;
#pragma unroll
      for (int c = 0; c < 4; ++c) {
        const int col = n0 + wn * 64 + c * 16 + (lane & 15);
#pragma unroll
        for (int j = 0; j < 4; ++j)
          C[(size_t)(row + j) * N + col] = f2bf(acc[r][c][j]);
      }
    }
  } else {
    float* C = (float*)Cout;
#pragma unroll
    for (int r = 0; r < 4; ++r) {
      const int row = m0 + wm * 64 + r * 16 + (lane >> 4) * 4;
#pragma unroll
      for (int c = 0; c < 4; ++c) {
        const int col = n0 + wn * 64 + c * 16 + (lane & 15);
#pragma unroll
        for (int j = 0; j < 4; ++j)
          C[(size_t)(row + j) * N + col] = acc[r][c][j];
      }
    }
  }
}

// ---------------- flash attention (non-causal, GQA) ----------------
// grid = B*H*(S/128) = 512 blocks; 4 waves, wave owns 32 q-rows (2 frags);
// KVBLK=64, K/V double-buffered in LDS with counted-vmcnt prefetch.
// LDS: K[2][64][128] swz ((row&7)<<3), V[2][128][64] swz, P[4][32][64] swz. 80 KB.
// Scores in log2 units (Q pre-scaled by log2e/sqrt(hd)); softmax = exp2.
// Defer-max (T13): skip od-rescale unless a row max grows past THR=8.

__global__ __launch_bounds__(256, 2) void attn_kernel(const unsigned short* __restrict__ Qb,
                                                      const unsigned short* __restrict__ Kb,
                                                      const unsigned short* __restrict__ Vt,
                                                      unsigned short* __restrict__ O) {
  __shared__ unsigned short Ks[2][64 * 128];   // 32 KB
  __shared__ unsigned short Vs[2][128 * 64];   // 32 KB
  __shared__ unsigned short Ps[4][32 * 64];    // 16 KB, per-wave P bounce
  const int tid = threadIdx.x, wid = tid >> 6, lane = tid & 63;
  const int blk = blockIdx.x;
  const int qt = blk & 15, h = (blk >> 4) & 15, b = blk >> 8;
  const int kvh = h >> 2;
  const int q0 = qt * 128 + wid * 32;

  const unsigned short* qhead = Qb + (size_t)((b * NH + h) * NS) * HD;
  const unsigned short* khead = Kb + (size_t)((b * NKV + kvh) * NS) * HD;
  const unsigned short* vhead = Vt + (size_t)((b * NKV + kvh) * HD) * NS;

  const int cl = lane & 15, g4 = (lane >> 4) * 4, hi8 = (lane >> 4) * 8;
  const int swk = (lane & 7) << 3;

  // stage one K/V tile (8 gload16 per wave) into buffer `buf`
  auto stageKV = [&](int buf, int kt) {
#pragma unroll
    for (int i = 0; i < 4; ++i) {
      int row = i * 16 + (tid >> 4);
      int col = ((tid & 15) * 8) ^ ((row & 7) << 3);
      gload16(khead + (size_t)(kt + row) * HD + col, &Ks[buf][i * 2048 + wid * 512]);
    }
#pragma unroll
    for (int i = 0; i < 4; ++i) {
      int row = i * 32 + (tid >> 3);
      int col = ((tid & 7) * 8) ^ ((row & 7) << 3);
      gload16(vhead + (size_t)row * NS + kt + col, &Vs[buf][i * 2048 + wid * 512]);
    }
  };

  stageKV(0, 0);   // prologue prefetch (in flight during qf loads)

  short8 qf[2][4];
#pragma unroll
  for (int r = 0; r < 2; ++r)
#pragma unroll
    for (int kk = 0; kk < 4; ++kk)
      qf[r][kk] = *(const short8*)(qhead + (size_t)(q0 + r * 16 + cl) * HD + kk * 32 + hi8);

  f32x4 od[2][8] = {};
  float mrun[2][4], lpart[2][4];
#pragma unroll
  for (int r = 0; r < 2; ++r)
#pragma unroll
    for (int j = 0; j < 4; ++j) { mrun[r][j] = -1e30f; lpart[r][j] = 0.0f; }

  int cur = 0;
  for (int it = 0; it < NS / 64; ++it) {
    // prefetch next tile, then wait only for the CURRENT tile's 8 loads
    if (it + 1 < NS / 64) {
      stageKV(cur ^ 1, (it + 1) * 64);
      asm volatile("s_waitcnt vmcnt(8)" ::: "memory");
    } else {
      asm volatile("s_waitcnt vmcnt(0)" ::: "memory");
    }
    __builtin_amdgcn_s_barrier();      // current tile visible to all waves

    const unsigned short* ks = Ks[cur];
    const unsigned short* vs = Vs[cur];

    // ---- QK^T: 32x64 scores per wave; K frags shared across both row frags ----
    f32x4 s[2][4];
#pragma unroll
    for (int r = 0; r < 2; ++r)
#pragma unroll
      for (int c4 = 0; c4 < 4; ++c4) s[r][c4] = f32x4{0.f, 0.f, 0.f, 0.f};
    __builtin_amdgcn_s_setprio(1);
#pragma unroll
    for (int c4 = 0; c4 < 4; ++c4)
#pragma unroll
      for (int kk = 0; kk < 4; ++kk) {
        short8 kf = *(const short8*)&ks[((c4 * 16 + cl) * 128 + kk * 32 + hi8) ^ swk];
        s[0][c4] = mfma16(qf[0][kk], kf, s[0][c4]);
        s[1][c4] = mfma16(qf[1][kk], kf, s[1][c4]);
      }
    __builtin_amdgcn_s_setprio(0);

    // ---- online softmax (log2 domain), defer-max across all 8 rows/lane ----
    float mt[2][4];
#pragma unroll
    for (int r = 0; r < 2; ++r)
#pragma unroll
      for (int j = 0; j < 4; ++j) {
        float m = fmaxf(fmaxf(s[r][0][j], s[r][1][j]), fmaxf(s[r][2][j], s[r][3][j]));
#pragma unroll
        for (int msk = 1; msk <= 8; msk <<= 1)
          m = fmaxf(m, __shfl_xor(m, msk, 64));
        mt[r][j] = m;
      }
    bool need = false;
#pragma unroll
    for (int r = 0; r < 2; ++r)
#pragma unroll
      for (int j = 0; j < 4; ++j)
        need = need || (mt[r][j] > mrun[r][j] + 8.0f);
    if (__any(need)) {
#pragma unroll
      for (int r = 0; r < 2; ++r)
#pragma unroll
        for (int j = 0; j < 4; ++j) {
          float mn = fmaxf(mrun[r][j], mt[r][j]);
          float corr = __builtin_amdgcn_exp2f(mrun[r][j] - mn);
          mrun[r][j] = mn;
          lpart[r][j] *= corr;
#pragma unroll
          for (int c = 0; c < 8; ++c)
            od[r][c][j] *= corr;
        }
    }
#pragma unroll
    for (int r = 0; r < 2; ++r)
#pragma unroll
      for (int j = 0; j < 4; ++j) {
        float acc = 0.f;
#pragma unroll
        for (int c4 = 0; c4 < 4; ++c4) {
          float p = __builtin_amdgcn_exp2f(s[r][c4][j] - mrun[r][j]);
          s[r][c4][j] = p;
          acc += p;
        }
        lpart[r][j] += acc;
      }

    // ---- P (32x64) -> LDS bf16, swizzled; re-read as PV A-fragments ----
    {
      unsigned short* pw = &Ps[wid][0];
#pragma unroll
      for (int r = 0; r < 2; ++r)
#pragma unroll
        for (int j = 0; j < 4; ++j) {
          const int row = r * 16 + g4 + j;
          const int sw = (row & 7) << 3;
#pragma unroll
          for (int c4 = 0; c4 < 4; ++c4)
            pw[(row * 64 + c4 * 16 + cl) ^ sw] = f2bf_fast(s[r][c4][j]);
        }
    }
    asm volatile("s_waitcnt lgkmcnt(0)" ::: "memory");
    __builtin_amdgcn_sched_barrier(0);
    short8 pa[2][2];
#pragma unroll
    for (int r = 0; r < 2; ++r) {
      pa[r][0] = *(const short8*)&Ps[wid][((r * 16 + cl) * 64 + hi8) ^ swk];
      pa[r][1] = *(const short8*)&Ps[wid][((r * 16 + cl) * 64 + 32 + hi8) ^ swk];
    }

    // ---- PV: od[r][c] += P_r(16x64) @ V(64x16); V frags shared across r ----
    __builtin_amdgcn_s_setprio(1);
#pragma unroll
    for (int c = 0; c < 8; ++c) {
      const int rr = c * 16 + cl;   // d-row in Vs
      short8 vf0 = *(const short8*)&vs[(rr * 64 + hi8) ^ swk];
      short8 vf1 = *(const short8*)&vs[(rr * 64 + 32 + hi8) ^ swk];
      od[0][c] = mfma16(pa[0][0], vf0, od[0][c]);
      od[0][c] = mfma16(pa[0][1], vf1, od[0][c]);
      od[1][c] = mfma16(pa[1][0], vf0, od[1][c]);
      od[1][c] = mfma16(pa[1][1], vf1, od[1][c]);
    }
    __builtin_amdgcn_s_setprio(0);
    __builtin_amdgcn_s_barrier();      // all waves done reading cur before overwrite
    cur ^= 1;
  }

  // ---- finalize: row sums + write O[B*S][H*hd] bf16 ----
  float linv[2][4];
#pragma unroll
  for (int r = 0; r < 2; ++r)
#pragma unroll
    for (int j = 0; j < 4; ++j) {
      float l = lpart[r][j];
#pragma unroll
      for (int msk = 1; msk <= 8; msk <<= 1)
        l += __shfl_xor(l, msk, 64);
      linv[r][j] = 1.0f / l;
    }
#pragma unroll
  for (int r = 0; r < 2; ++r) {
    const int orow0 = b * NS + q0 + r * 16 + g4;
#pragma unroll
    for (int c = 0; c < 8; ++c)
#pragma unroll
      for (int j = 0; j < 4; ++j)
        O[(size_t)(orow0 + j) * ND + h * HD + c * 16 + cl] = f2bf(od[r][c][j] * linv[r][j]);
  }
}

// ---------------- launch ----------------

extern "C" void kernel_launch(void* const* d_in, const int* in_sizes, int n_in,
                              void* d_out, int out_size, void* d_ws, size_t ws_size,
                              hipStream_t stream) {
  const float* x  = (const float*)d_in[0];
  const float* wq = (const float*)d_in[1];
  const float* wk = (const float*)d_in[2];
  const float* wv = (const float*)d_in[3];
  const float* wo = (const float*)d_in[4];
  float* out = (float*)d_out;
  char* ws = (char*)d_ws;

  // ws layout (bytes); total needed = 63,963,136
  unsigned short* xb   = (unsigned short*)(ws + 0);          // 16.8 MB [4096][2048] bf16
  unsigned short* wT   = (unsigned short*)(ws + 16777216);   // 12.6 MB [3072][2048] bf16 (wq|wk|wv)^T
  unsigned short* woT  = (unsigned short*)(ws + 29360128);   //  8.4 MB [2048][2048] bf16
  float2*         tab  = (float2*)(ws + 37748736);           //  1.0 MB [2048][64] cos/sin
  unsigned short* QKV  = (unsigned short*)(ws + 38797312);   // 25.2 MB [4096][3072] bf16
  unsigned short* Qb   = xb;                                 // alias: xb dead after GEMM1
  unsigned short* Kb   = wT;                                 // alias: wT dead after GEMM1
  unsigned short* Vt   = (unsigned short*)(ws + 16777216 + 4194304);
  unsigned short* Obuf = QKV;                                // alias: QKV dead after scatter

  convert_x_kernel<<<8192, 256, 0, stream>>>(x, xb);
  transpose_w_kernel<<<dim3(32, 32), 256, 0, stream>>>(wq, wT, 2048, 2048);
  transpose_w_kernel<<<dim3(32, 8),  256, 0, stream>>>(wk, wT + (size_t)2048 * 2048, 2048, 512);
  transpose_w_kernel<<<dim3(32, 8),  256, 0, stream>>>(wv, wT + (size_t)2560 * 2048, 2048, 512);
  transpose_w_kernel<<<dim3(32, 32), 256, 0, stream>>>(wo, woT, 2048, 2048);
  rope_table_kernel<<<512, 256, 0, stream>>>(tab);

  gemm_kernel<NQKV, true><<<dim3(32, 24), 256, 0, stream>>>(xb, wT, QKV);

  rope_scatter_kernel<<<20480, 256, 0, stream>>>(QKV, tab, Qb, Kb);
  transpose_v_kernel<<<dim3(8, 32, 2), 256, 0, stream>>>(QKV, Vt);

  attn_kernel<<<512, 256, 0, stream>>>(Qb, Kb, Vt, Obuf);

  gemm_kernel<ND, false><<<dim3(32, 16), 256, 0, stream>>>(Obuf, woT, out);
}

// Round 4
// 248.393 us; speedup vs baseline: 1.3890x; 1.0855x over previous
//
#include <hip/hip_runtime.h>

// ---------------------------------------------------------------------------
// MHA (GQA + RoPE, non-causal) on MI355X, bf16 MFMA pipeline, fp32 in/out.
// B=2 S=2048 D=2048 H=16 KV=4 hd=128.
// R4: attention swapped QK^T (P[k][q] lane-local) + in-register P
//     redistribution via v_permlane32/16_swap (T12) — no P LDS bounce,
//     softmax reduce = 15 fmax + 2 shfl per frag. K/V double-buffer with
//     counted vmcnt unchanged from R3.
// ---------------------------------------------------------------------------

typedef __attribute__((ext_vector_type(8))) short short8;
typedef __attribute__((ext_vector_type(4))) float f32x4;

#define DEV static __device__ __forceinline__

#define NB 2
#define NS 2048
#define ND 2048
#define NH 16
#define NKV 4
#define HD 128
#define NQKV 3072   // H*hd + 2*KV*hd

DEV unsigned short f2bf(float f) {
  union { float f; unsigned u; } v; v.f = f;
  unsigned r = v.u + 0x7fffu + ((v.u >> 16) & 1u);   // RNE
  return (unsigned short)(r >> 16);
}
DEV unsigned short f2bf_fast(float f) {            // round-to-nearest (cheap)
  union { float f; unsigned u; } v; v.f = f;
  return (unsigned short)((v.u + 0x8000u) >> 16);
}
DEV float bf2f(unsigned short u) {
  union { unsigned u; float f; } v; v.u = ((unsigned)u) << 16; return v.f;
}
DEV unsigned pack2bf(float a, float b) {           // [bf16(a) | bf16(b)<<16]
  return (unsigned)f2bf_fast(a) | ((unsigned)f2bf_fast(b) << 16);
}
DEV unsigned pack2bf_rne(float a, float b) {
  return (unsigned)f2bf(a) | ((unsigned)f2bf(b) << 16);
}

// gfx950 permlane swaps: both operands are read+written.
// swap32: x' = [x.lanes0-31 | y.lanes0-31], y' = [x.lanes32-63 | y.lanes32-63]
DEV void swap32(unsigned &x, unsigned &y) {
  asm volatile("v_permlane32_swap_b32 %0, %1" : "+v"(x), "+v"(y));
}
// swap16 (rows = 16-lane groups): x' = [x.r0, y.r0, x.r2, y.r2], y' = [x.r1, y.r1, x.r3, y.r3]
DEV void swap16(unsigned &x, unsigned &y) {
  asm volatile("v_permlane16_swap_b32 %0, %1" : "+v"(x), "+v"(y));
}

typedef const __attribute__((address_space(1))) void* gas1_t;
typedef __attribute__((address_space(3))) void* las3_t;
DEV void gload16(const void* g, void* l) {
  // global -> LDS direct, 16B/lane; LDS dest = wave-uniform base + lane*16.
  __builtin_amdgcn_global_load_lds((gas1_t)g, (las3_t)l, 16, 0, 0);
}

DEV f32x4 mfma16(short8 a, short8 b, f32x4 c) {
  return __builtin_amdgcn_mfma_f32_16x16x32_bf16(a, b, c, 0, 0, 0);
}

// ---------------- prep kernels ----------------

__global__ __launch_bounds__(256) void convert_x_kernel(const float* __restrict__ x,
                                                        unsigned short* __restrict__ xb) {
  size_t i = ((size_t)blockIdx.x * 256 + threadIdx.x) * 4;
  float4 v = *(const float4*)(x + i);
  unsigned long long pack = (unsigned long long)f2bf(v.x)
                          | ((unsigned long long)f2bf(v.y) << 16)
                          | ((unsigned long long)f2bf(v.z) << 32)
                          | ((unsigned long long)f2bf(v.w) << 48);
  *(unsigned long long*)(xb + i) = pack;
}

// src [K][N] fp32 -> dst [N][K] bf16 (LDS tiled transpose, 64x64 tiles)
__global__ __launch_bounds__(256) void transpose_w_kernel(const float* __restrict__ src,
                                                          unsigned short* __restrict__ dst,
                                                          int K, int N) {
  __shared__ float tile[64][65];
  const int k0 = blockIdx.x * 64, n0 = blockIdx.y * 64;
  for (int i = threadIdx.x; i < 4096; i += 256) {
    int r = i >> 6, c = i & 63;
    tile[r][c] = src[(size_t)(k0 + r) * N + n0 + c];
  }
  __syncthreads();
  for (int i = threadIdx.x; i < 4096; i += 256) {
    int r = i >> 6, c = i & 63;
    dst[(size_t)(n0 + r) * K + k0 + c] = f2bf(tile[c][r]);
  }
}

__global__ __launch_bounds__(256) void rope_table_kernel(float2* __restrict__ tab) {
  int t = blockIdx.x * 256 + threadIdx.x;        // S*64 = 131072
  int s = t >> 6, i = t & 63;
  float freq = powf(10000.0f, -(float)i * (1.0f / 64.0f));
  float ang = (float)s * freq;
  tab[t] = make_float2(cosf(ang), sinf(ang));
}

// QKV [4096][3072] bf16 -> Qb [B][H][S][hd] (rope, *log2e/sqrt(hd)), Kb (rope)
__global__ __launch_bounds__(256) void rope_scatter_kernel(const unsigned short* __restrict__ QKV,
                                                           const float2* __restrict__ tab,
                                                           unsigned short* __restrict__ Qb,
                                                           unsigned short* __restrict__ Kb) {
  int t = blockIdx.x * 256 + threadIdx.x;
  const float qscale = 0.12751741161895452f;     // (1/sqrt(128)) * log2(e)
  if (t < (1 << 22)) {                           // Q pairs: B*S*H*64 = 2^22
    int i = t & 63, h = (t >> 6) & 15, s = (t >> 10) & 2047, b = t >> 21;
    const unsigned short* p = QKV + (size_t)(b * NS + s) * NQKV + h * HD + 2 * i;
    float2 cs = tab[s * 64 + i];
    float x1 = bf2f(p[0]), x2 = bf2f(p[1]);
    unsigned short* q = Qb + (size_t)((b * NH + h) * NS + s) * HD + 2 * i;
    q[0] = f2bf((x1 * cs.x - x2 * cs.y) * qscale);
    q[1] = f2bf((x1 * cs.y + x2 * cs.x) * qscale);
  } else {                                       // K pairs: B*S*KV*64 = 2^20
    int u = t - (1 << 22);
    int i = u & 63, kv = (u >> 6) & 3, s = (u >> 8) & 2047, b = u >> 19;
    const unsigned short* p = QKV + (size_t)(b * NS + s) * NQKV + 2048 + kv * HD + 2 * i;
    float2 cs = tab[s * 64 + i];
    float x1 = bf2f(p[0]), x2 = bf2f(p[1]);
    unsigned short* k = Kb + (size_t)((b * NKV + kv) * NS + s) * HD + 2 * i;
    k[0] = f2bf(x1 * cs.x - x2 * cs.y);
    k[1] = f2bf(x1 * cs.y + x2 * cs.x);
  }
}

// V columns of QKV -> Vt [B][KV][hd][S] bf16 (transposed for PV A-fragments)
__global__ __launch_bounds__(256) void transpose_v_kernel(const unsigned short* __restrict__ QKV,
                                                          unsigned short* __restrict__ Vt) {
  __shared__ unsigned short tile[64][65];
  const int bk = blockIdx.x, b = bk >> 2, kv = bk & 3;
  const int s0 = blockIdx.y * 64, d0 = blockIdx.z * 64;
  for (int i = threadIdx.x; i < 4096; i += 256) {
    int r = i >> 6, c = i & 63;   // r = s-offset, c = d-offset
    tile[r][c] = QKV[(size_t)(b * NS + s0 + r) * NQKV + 2560 + kv * HD + d0 + c];
  }
  __syncthreads();
  for (int i = threadIdx.x; i < 4096; i += 256) {
    int r = i >> 6, c = i & 63;   // r = d-offset, c = s-offset
    Vt[(size_t)((b * NKV + kv) * HD + d0 + r) * NS + s0 + c] = tile[c][r];
  }
}

// ---------------- GEMM: C[M][N] = A[M][K=2048] * Bt[N][K]^T, bf16 in, acc fp32 ----------------
// 128x128 tile, BK=32, 4 waves (2x2), m97 structure (global_load_lds staging).

template <int N, bool OUTBF16>
__global__ __launch_bounds__(256) void gemm_kernel(const unsigned short* __restrict__ A,
                                                   const unsigned short* __restrict__ Bt,
                                                   void* __restrict__ Cout) {
  __shared__ unsigned short As[128 * 32];  // 8 KB
  __shared__ unsigned short Bs[128 * 32];
  const int K = 2048;
  const int tid = threadIdx.x, wid = tid >> 6, lane = tid & 63;
  const int wm = wid >> 1, wn = wid & 1;
  const int m0 = blockIdx.x * 128, n0 = blockIdx.y * 128;
  f32x4 acc[4][4] = {};
  const int srow = tid >> 2;           // 0..63
  const int scol = (tid & 3) * 8;
  const unsigned short* Ab = A + (size_t)(m0 + srow) * K + scol;
  const unsigned short* Ab2 = Ab + (size_t)64 * K;
  const unsigned short* Bb = Bt + (size_t)(n0 + srow) * K + scol;
  const unsigned short* Bb2 = Bb + (size_t)64 * K;

  for (int kt = 0; kt < K; kt += 32) {
    gload16(Ab + kt, &As[wid * 512]);
    gload16(Ab2 + kt, &As[2048 + wid * 512]);
    gload16(Bb + kt, &Bs[wid * 512]);
    gload16(Bb2 + kt, &Bs[2048 + wid * 512]);
    __syncthreads();                   // drains vmcnt before use
    short8 af[4], bfr[4];
#pragma unroll
    for (int r = 0; r < 4; ++r)
      af[r] = *(const short8*)&As[(wm * 64 + r * 16 + (lane & 15)) * 32 + (lane >> 4) * 8];
#pragma unroll
    for (int c = 0; c < 4; ++c)
      bfr[c] = *(const short8*)&Bs[(wn * 64 + c * 16 + (lane & 15)) * 32 + (lane >> 4) * 8];
    __builtin_amdgcn_s_setprio(1);
#pragma unroll
    for (int r = 0; r < 4; ++r)
#pragma unroll
      for (int c = 0; c < 4; ++c)
        acc[r][c] = mfma16(af[r], bfr[c], acc[r][c]);
    __builtin_amdgcn_s_setprio(0);
    __syncthreads();
  }

  // epilogue: C row = m0 + wm*64 + r*16 + (lane>>4)*4 + j ; col = n0 + wn*64 + c*16 + (lane&15)
  if (OUTBF16) {
    unsigned short* C = (unsigned short*)Cout;
#pragma unroll
    for (int r = 0; r < 4; ++r) {
      const int row = m0 + wm * 64 + r * 16 + (lane >> 4) * 4;
#pragma unroll
      for (int c = 0; c < 4; ++c) {
        const int col = n0 + wn * 64 + c * 16 + (lane & 15);
#pragma unroll
        for (int j = 0; j < 4; ++j)
          C[(size_t)(row + j) * N + col] = f2bf(acc[r][c][j]);
      }
    }
  } else {
    float* C = (float*)Cout;
#pragma unroll
    for (int r = 0; r < 4; ++r) {
      const int row = m0 + wm * 64 + r * 16 + (lane >> 4) * 4;
#pragma unroll
      for (int c = 0; c < 4; ++c) {
        const int col = n0 + wn * 64 + c * 16 + (lane & 15);
#pragma unroll
        for (int j = 0; j < 4; ++j)
          C[(size_t)(row + j) * N + col] = acc[r][c][j];
      }
    }
  }
}

// ---------------- flash attention (non-causal, GQA) ----------------
// grid = B*H*(S/128) = 512 blocks; 4 waves, wave owns 32 q-rows (2 q-frags);
// KVBLK=64, K/V double-buffered in LDS with counted-vmcnt prefetch.
// SWAPPED QK^T: s[r][c4] = mfma(K_frag, Q_frag) -> P[k][q], q = lane&15 fixed.
// P redistributed to PV B-frags IN REGISTERS via permlane32/16 swaps (T12).
// LDS: K[2][64][128] swz ((row&7)<<3), V[2][128][64] swz. 64 KB.
// Scores in log2 units (Q pre-scaled by log2e/sqrt(hd)); softmax = exp2.
// Defer-max (T13): skip od-rescale unless a row max grows past THR=8.

__global__ __launch_bounds__(256, 2) void attn_kernel(const unsigned short* __restrict__ Qb,
                                                      const unsigned short* __restrict__ Kb,
                                                      const unsigned short* __restrict__ Vt,
                                                      unsigned short* __restrict__ O) {
  __shared__ unsigned short Ks[2][64 * 128];   // 32 KB
  __shared__ unsigned short Vs[2][128 * 64];   // 32 KB
  const int tid = threadIdx.x, wid = tid >> 6, lane = tid & 63;
  const int blk = blockIdx.x;
  const int qt = blk & 15, h = (blk >> 4) & 15, b = blk >> 8;
  const int kvh = h >> 2;
  const int q0 = qt * 128 + wid * 32;

  const unsigned short* qhead = Qb + (size_t)((b * NH + h) * NS) * HD;
  const unsigned short* khead = Kb + (size_t)((b * NKV + kvh) * NS) * HD;
  const unsigned short* vhead = Vt + (size_t)((b * NKV + kvh) * HD) * NS;

  const int cl = lane & 15, g4 = (lane >> 4) * 4, hi8 = (lane >> 4) * 8;
  const int swk = (lane & 7) << 3;

  // stage one K/V tile (8 gload16 per wave) into buffer `buf`
  auto stageKV = [&](int buf, int kt) {
#pragma unroll
    for (int i = 0; i < 4; ++i) {
      int row = i * 16 + (tid >> 4);
      int col = ((tid & 15) * 8) ^ ((row & 7) << 3);
      gload16(khead + (size_t)(kt + row) * HD + col, &Ks[buf][i * 2048 + wid * 512]);
    }
#pragma unroll
    for (int i = 0; i < 4; ++i) {
      int row = i * 32 + (tid >> 3);
      int col = ((tid & 7) * 8) ^ ((row & 7) << 3);
      gload16(vhead + (size_t)row * NS + kt + col, &Vs[buf][i * 2048 + wid * 512]);
    }
  };

  stageKV(0, 0);   // prologue prefetch (in flight during qf loads)

  short8 qf[2][4];
#pragma unroll
  for (int r = 0; r < 2; ++r)
#pragma unroll
    for (int kk = 0; kk < 4; ++kk)
      qf[r][kk] = *(const short8*)(qhead + (size_t)(q0 + r * 16 + cl) * HD + kk * 32 + hi8);

  f32x4 od[2][8] = {};
  float mrun[2] = {-1e30f, -1e30f}, lpart[2] = {0.f, 0.f};

  int cur = 0;
  for (int it = 0; it < NS / 64; ++it) {
    // prefetch next tile, then wait only for the CURRENT tile's 8 loads
    if (it + 1 < NS / 64) {
      stageKV(cur ^ 1, (it + 1) * 64);
      asm volatile("s_waitcnt vmcnt(8)" ::: "memory");
    } else {
      asm volatile("s_waitcnt vmcnt(0)" ::: "memory");
    }
    __builtin_amdgcn_s_barrier();      // current tile visible to all waves

    const unsigned short* ks = Ks[cur];
    const unsigned short* vs = Vs[cur];

    // ---- swapped QK^T: s[r][c4][j] = P[k = c4*16 + (lane>>4)*4 + j][q = q0+16r+cl] ----
    f32x4 s[2][4];
#pragma unroll
    for (int r = 0; r < 2; ++r)
#pragma unroll
      for (int c4 = 0; c4 < 4; ++c4) s[r][c4] = f32x4{0.f, 0.f, 0.f, 0.f};
    __builtin_amdgcn_s_setprio(1);
#pragma unroll
    for (int c4 = 0; c4 < 4; ++c4)
#pragma unroll
      for (int kk = 0; kk < 4; ++kk) {
        short8 kf = *(const short8*)&ks[((c4 * 16 + cl) * 128 + kk * 32 + hi8) ^ swk];
        s[0][c4] = mfma16(kf, qf[0][kk], s[0][c4]);
        s[1][c4] = mfma16(kf, qf[1][kk], s[1][c4]);
      }
    __builtin_amdgcn_s_setprio(0);

    // ---- online softmax (log2 domain): k is lane-local, q = cl fixed ----
    float mt[2];
#pragma unroll
    for (int r = 0; r < 2; ++r) {
      float m = fmaxf(fmaxf(fmaxf(s[r][0][0], s[r][0][1]), fmaxf(s[r][0][2], s[r][0][3])),
                      fmaxf(fmaxf(s[r][1][0], s[r][1][1]), fmaxf(s[r][1][2], s[r][1][3])));
      float m2 = fmaxf(fmaxf(fmaxf(s[r][2][0], s[r][2][1]), fmaxf(s[r][2][2], s[r][2][3])),
                       fmaxf(fmaxf(s[r][3][0], s[r][3][1]), fmaxf(s[r][3][2], s[r][3][3])));
      m = fmaxf(m, m2);
      m = fmaxf(m, __shfl_xor(m, 16, 64));
      m = fmaxf(m, __shfl_xor(m, 32, 64));
      mt[r] = m;
    }
    bool need = (mt[0] > mrun[0] + 8.0f) || (mt[1] > mrun[1] + 8.0f);
    if (__any(need)) {
#pragma unroll
      for (int r = 0; r < 2; ++r) {
        float mn = fmaxf(mrun[r], mt[r]);
        float corr = __builtin_amdgcn_exp2f(mrun[r] - mn);
        mrun[r] = mn;
        lpart[r] *= corr;
#pragma unroll
        for (int c = 0; c < 8; ++c)
          od[r][c] *= corr;
      }
    }
#pragma unroll
    for (int r = 0; r < 2; ++r) {
      float acc = 0.f;
#pragma unroll
      for (int c4 = 0; c4 < 4; ++c4)
#pragma unroll
        for (int j = 0; j < 4; ++j) {
          float p = __builtin_amdgcn_exp2f(s[r][c4][j] - mrun[r]);
          s[r][c4][j] = p;
          acc += p;
        }
      lpart[r] += acc;
    }

    // ---- pack P to bf16 pairs and redistribute to PV B-frags in registers ----
    // word(c4,w) holds k = {16c4+4g+2w, +1}; target pb[half] word w' holds k = {8g+2w', +1}.
    // swap32 then swap16 on (A=word(2h,w), B=word(2h+1,w)) -> pb words w and w+2.
    short8 pb[2][2];
#pragma unroll
    for (int r = 0; r < 2; ++r) {
      unsigned w00 = pack2bf(s[r][0][0], s[r][0][1]), w01 = pack2bf(s[r][0][2], s[r][0][3]);
      unsigned w10 = pack2bf(s[r][1][0], s[r][1][1]), w11 = pack2bf(s[r][1][2], s[r][1][3]);
      unsigned w20 = pack2bf(s[r][2][0], s[r][2][1]), w21 = pack2bf(s[r][2][2], s[r][2][3]);
      unsigned w30 = pack2bf(s[r][3][0], s[r][3][1]), w31 = pack2bf(s[r][3][2], s[r][3][3]);
      union { unsigned u[4]; short8 v; } t0, t1;
      swap32(w00, w10); swap16(w00, w10); t0.u[0] = w00; t0.u[2] = w10;
      swap32(w01, w11); swap16(w01, w11); t0.u[1] = w01; t0.u[3] = w11;
      swap32(w20, w30); swap16(w20, w30); t1.u[0] = w20; t1.u[2] = w30;
      swap32(w21, w31); swap16(w21, w31); t1.u[1] = w21; t1.u[3] = w31;
      pb[r][0] = t0.v;   // k 0..31
      pb[r][1] = t1.v;   // k 32..63
    }

    // ---- PV (swapped): od[r][c] = V^T-block(c) @ P-frag; A=V rows=d, B=P cols=q ----
    __builtin_amdgcn_s_setprio(1);
#pragma unroll
    for (int c = 0; c < 8; ++c) {
      const int rr = c * 16 + cl;   // d-row in Vs
      short8 vf0 = *(const short8*)&vs[(rr * 64 + hi8) ^ swk];
      short8 vf1 = *(const short8*)&vs[(rr * 64 + 32 + hi8) ^ swk];
      od[0][c] = mfma16(vf0, pb[0][0], od[0][c]);
      od[0][c] = mfma16(vf1, pb[0][1], od[0][c]);
      od[1][c] = mfma16(vf0, pb[1][0], od[1][c]);
      od[1][c] = mfma16(vf1, pb[1][1], od[1][c]);
    }
    __builtin_amdgcn_s_setprio(0);
    __builtin_amdgcn_s_barrier();      // all waves done reading cur before overwrite
    cur ^= 1;
  }

  // ---- finalize: cross-group l-sum + packed 8B stores ----
  float linv[2];
#pragma unroll
  for (int r = 0; r < 2; ++r) {
    float l = lpart[r];
    l += __shfl_xor(l, 16, 64);
    l += __shfl_xor(l, 32, 64);
    linv[r] = 1.0f / l;
  }
#pragma unroll
  for (int r = 0; r < 2; ++r) {
    const size_t row = (size_t)(b * NS + q0 + 16 * r + cl);
#pragma unroll
    for (int c = 0; c < 8; ++c) {
      uint2 pk;
      pk.x = pack2bf_rne(od[r][c][0] * linv[r], od[r][c][1] * linv[r]);
      pk.y = pack2bf_rne(od[r][c][2] * linv[r], od[r][c][3] * linv[r]);
      *(uint2*)(O + row * ND + h * HD + c * 16 + g4) = pk;
    }
  }
}

// ---------------- launch ----------------

extern "C" void kernel_launch(void* const* d_in, const int* in_sizes, int n_in,
                              void* d_out, int out_size, void* d_ws, size_t ws_size,
                              hipStream_t stream) {
  const float* x  = (const float*)d_in[0];
  const float* wq = (const float*)d_in[1];
  const float* wk = (const float*)d_in[2];
  const float* wv = (const float*)d_in[3];
  const float* wo = (const float*)d_in[4];
  float* out = (float*)d_out;
  char* ws = (char*)d_ws;

  // ws layout (bytes); total needed = 63,963,136
  unsigned short* xb   = (unsigned short*)(ws + 0);          // 16.8 MB [4096][2048] bf16
  unsigned short* wT   = (unsigned short*)(ws + 16777216);   // 12.6 MB [3072][2048] bf16 (wq|wk|wv)^T
  unsigned short* woT  = (unsigned short*)(ws + 29360128);   //  8.4 MB [2048][2048] bf16
  float2*         tab  = (float2*)(ws + 37748736);           //  1.0 MB [2048][64] cos/sin
  unsigned short* QKV  = (unsigned short*)(ws + 38797312);   // 25.2 MB [4096][3072] bf16
  unsigned short* Qb   = xb;                                 // alias: xb dead after GEMM1
  unsigned short* Kb   = wT;                                 // alias: wT dead after GEMM1
  unsigned short* Vt   = (unsigned short*)(ws + 16777216 + 4194304);
  unsigned short* Obuf = QKV;                                // alias: QKV dead after scatter

  convert_x_kernel<<<8192, 256, 0, stream>>>(x, xb);
  transpose_w_kernel<<<dim3(32, 32), 256, 0, stream>>>(wq, wT, 2048, 2048);
  transpose_w_kernel<<<dim3(32, 8),  256, 0, stream>>>(wk, wT + (size_t)2048 * 2048, 2048, 512);
  transpose_w_kernel<<<dim3(32, 8),  256, 0, stream>>>(wv, wT + (size_t)2560 * 2048, 2048, 512);
  transpose_w_kernel<<<dim3(32, 32), 256, 0, stream>>>(wo, woT, 2048, 2048);
  rope_table_kernel<<<512, 256, 0, stream>>>(tab);

  gemm_kernel<NQKV, true><<<dim3(32, 24), 256, 0, stream>>>(xb, wT, QKV);

  rope_scatter_kernel<<<20480, 256, 0, stream>>>(QKV, tab, Qb, Kb);
  transpose_v_kernel<<<dim3(8, 32, 2), 256, 0, stream>>>(QKV, Vt);

  attn_kernel<<<512, 256, 0, stream>>>(Qb, Kb, Vt, Obuf);

  gemm_kernel<ND, false><<<dim3(32, 16), 256, 0, stream>>>(Obuf, woT, out);
}